// Round 20
// baseline (256.039 us; speedup 1.0000x reference)
//
#include <hip/hip_runtime.h>
#include <hip/hip_bf16.h>
#include <math.h>

// ChebyNet: 2-layer ChebConv (K=4), N=100000, E=1600000, F 32->16->10, log_softmax.
//
// R20 = R19 + edge-split gather parallelism: prop_cl/final1/final2 move from
// 2 to 4 lanes/node (lane = (chunk, edge-half)); each lane gathers half the
// node's edge list for its chunk, one shfl_xor(2) merges halves. Gather/psrc
// traffic unchanged; waves double (12 -> 25/CU) and the dependent gather
// chain halves -- attacks the latency-bound regime the 2-lane version was in.
// R18/R19 recap: Clenshaw (z_k = x@W1[k] first; all gathers in 16-feature
// domain, 3.2MB L2-resident tables), U-space folding, fixed-capacity bucket
// CSR build (CHUNK=4096), src-quartile edge ordering, deg-0 exact fallback.

#define BLK 256
#define BLKP 512
#define NBUCK_MAX 256   // buckets = ceil(N/512); requires N <= 131072
#define CHUNK 4096      // edges per binned_scatter block
#define CAPB 16384      // fixed capacity per bucket region in tmp/psrc
#define PLACE_CAP 10240 // LDS staging capacity in bucket_place (avg bucket 8192)

// ---------- bf16 helpers (storage-only quantization) ----------
__device__ inline unsigned short f32_to_bf16_rne(float f) {
    unsigned int u = __float_as_uint(f);
    unsigned int rounding = 0x7FFFu + ((u >> 16) & 1u);
    return (unsigned short)((u + rounding) >> 16);
}
__device__ inline unsigned int pack_bf16x2(float a, float b) {
    return (unsigned int)f32_to_bf16_rne(a) | ((unsigned int)f32_to_bf16_rne(b) << 16);
}
__device__ inline void unpack8(const uint4 u, float* f) {
    const unsigned int* p = &u.x;
#pragma unroll
    for (int j = 0; j < 4; j++) {
        unsigned int w = p[j];
        f[2 * j]     = __uint_as_float(w << 16);
        f[2 * j + 1] = __uint_as_float(w & 0xFFFF0000u);
    }
}
__device__ inline void add8(const uint4 u, float* acc) {
    const unsigned int* p = &u.x;
#pragma unroll
    for (int j = 0; j < 4; j++) {
        unsigned int w = p[j];
        acc[2 * j]     += __uint_as_float(w << 16);
        acc[2 * j + 1] += __uint_as_float(w & 0xFFFF0000u);
    }
}
__device__ inline uint4 pack8(const float* r) {
    uint4 o;
    o.x = pack_bf16x2(r[0], r[1]);
    o.y = pack_bf16x2(r[2], r[3]);
    o.z = pack_bf16x2(r[4], r[5]);
    o.w = pack_bf16x2(r[6], r[7]);
    return o;
}

// gather-sum over psrc[b,e) of vb chunk c
__device__ inline void gather_sum(const int* __restrict__ psrc, int b, int e,
                                  const uint4* __restrict__ vb, int c, float* acc) {
    int i = b;
    for (; i + 7 < e; i += 8) {
        int s0 = psrc[i],     s1 = psrc[i + 1], s2 = psrc[i + 2], s3 = psrc[i + 3];
        int s4 = psrc[i + 4], s5 = psrc[i + 5], s6 = psrc[i + 6], s7 = psrc[i + 7];
        uint4 a0 = vb[(size_t)s0 * 2 + c];
        uint4 a1 = vb[(size_t)s1 * 2 + c];
        uint4 a2 = vb[(size_t)s2 * 2 + c];
        uint4 a3 = vb[(size_t)s3 * 2 + c];
        uint4 a4 = vb[(size_t)s4 * 2 + c];
        uint4 a5 = vb[(size_t)s5 * 2 + c];
        uint4 a6 = vb[(size_t)s6 * 2 + c];
        uint4 a7 = vb[(size_t)s7 * 2 + c];
        add8(a0, acc); add8(a1, acc); add8(a2, acc); add8(a3, acc);
        add8(a4, acc); add8(a5, acc); add8(a6, acc); add8(a7, acc);
    }
    for (; i + 3 < e; i += 4) {
        int s0 = psrc[i], s1 = psrc[i + 1], s2 = psrc[i + 2], s3 = psrc[i + 3];
        uint4 a0 = vb[(size_t)s0 * 2 + c];
        uint4 a1 = vb[(size_t)s1 * 2 + c];
        uint4 a2 = vb[(size_t)s2 * 2 + c];
        uint4 a3 = vb[(size_t)s3 * 2 + c];
        add8(a0, acc); add8(a1, acc); add8(a2, acc); add8(a3, acc);
    }
    for (; i < e; i++) add8(vb[(size_t)psrc[i] * 2 + c], acc);
}

// ---------- CSR build (fixed-capacity buckets) ----------
__global__ __launch_bounds__(BLK)
void binned_scatter_kernel(const int* __restrict__ src, const int* __restrict__ dst,
                           int* __restrict__ bfill, int* __restrict__ tmp,
                           int E, int nbuck) {
    __shared__ int cnt[NBUCK_MAX];
    __shared__ int lofs[NBUCK_MAX + 1];
    __shared__ int pos[NBUCK_MAX];
    __shared__ int gbase[NBUCK_MAX];
    __shared__ int stage[CHUNK];
    __shared__ unsigned char bkt[CHUNK];

    int tid = threadIdx.x;
    int e0 = blockIdx.x * CHUNK;
    int nE = min(CHUNK, E - e0);

    for (int b = tid; b < nbuck; b += BLK) { cnt[b] = 0; pos[b] = 0; }
    __syncthreads();

    for (int i = tid; i < nE; i += BLK) {
        int d = dst[e0 + i];
        atomicAdd(&cnt[d >> 9], 1);
    }
    __syncthreads();

    {
        int v = (tid < nbuck) ? cnt[tid] : 0;
        lofs[tid] = v;
        __syncthreads();
        for (int off = 1; off < BLK; off <<= 1) {
            int t = (tid >= off) ? lofs[tid - off] : 0;
            __syncthreads();
            lofs[tid] += t;
            __syncthreads();
        }
        int incl = lofs[tid];
        __syncthreads();
        lofs[tid] = incl - v;
        if (tid == 0) lofs[nbuck] = nE;
        if (tid < nbuck && v > 0)
            gbase[tid] = tid * CAPB + atomicAdd(&bfill[tid], v);
    }
    __syncthreads();

    for (int i = tid; i < nE; i += BLK) {
        int s = src[e0 + i];
        int d = dst[e0 + i];
        int b = d >> 9;
        int slot = lofs[b] + atomicAdd(&pos[b], 1);
        stage[slot] = (s << 9) | (d & 511);
        bkt[slot] = (unsigned char)b;
    }
    __syncthreads();

    for (int i = tid; i < nE; i += BLK) {
        int b = bkt[i];
        tmp[gbase[b] + (i - lofs[b])] = stage[i];
    }
}

// Phase 2: per-bucket degree count/scan -> rowbeg/rowend/dis/d2/inv;
// rank+stage+flush psrc with each node's edges ordered by src quartile.
__global__ __launch_bounds__(BLKP)
void bucket_place_kernel(const int* __restrict__ bfill, const int* __restrict__ tmp,
                         int* __restrict__ psrc, int* __restrict__ rowbeg,
                         int* __restrict__ rowend, float* __restrict__ dis,
                         float* __restrict__ d2, float* __restrict__ inv, int N) {
    __shared__ int cnt4[512 * 4];
    __shared__ int ofs[512];
    __shared__ int fill4[512 * 4];
    __shared__ int stage[PLACE_CAP];

    int b = blockIdx.x;
    int tid = threadIdx.x;
    int n0 = b << 9;
    int nn = min(512, N - n0);
    int S = b * CAPB;
    int tot = bfill[b];

    int t1 = N >> 2, t2 = N >> 1, t3 = t2 + t1;

    for (int i = tid; i < 512 * 4; i += BLKP) { cnt4[i] = 0; fill4[i] = 0; }
    __syncthreads();

    for (int i = tid; i < tot; i += BLKP) {
        int rec = tmp[S + i];
        int nl = rec & 511;
        int s = rec >> 9;
        int q = (s >= t2) ? ((s >= t3) ? 3 : 2) : ((s >= t1) ? 1 : 0);
        atomicAdd(&cnt4[nl * 4 + q], 1);
    }
    __syncthreads();

    int c0 = cnt4[tid * 4 + 0], c1 = cnt4[tid * 4 + 1];
    int c2 = cnt4[tid * 4 + 2], c3 = cnt4[tid * 4 + 3];
    int v = c0 + c1 + c2 + c3;
    cnt4[tid * 4 + 0] = 0;
    cnt4[tid * 4 + 1] = c0;
    cnt4[tid * 4 + 2] = c0 + c1;
    cnt4[tid * 4 + 3] = c0 + c1 + c2;
    ofs[tid] = v;
    __syncthreads();
    for (int off = 1; off < 512; off <<= 1) {
        int t = (tid >= off) ? ofs[tid - off] : 0;
        __syncthreads();
        ofs[tid] += t;
        __syncthreads();
    }
    int excl = ofs[tid] - v;
    __syncthreads();
    ofs[tid] = excl;
    if (tid < nn) {
        int n = n0 + tid;
        rowbeg[n] = S + excl;
        rowend[n] = S + excl + v;
        float fv = (float)v;
        dis[n] = (v > 0) ? rsqrtf(fv) : 0.0f;
        d2[n]  = (v > 0) ? 1.0f / fv : 0.0f;
        inv[n] = (v > 0) ? sqrtf(fv) : 0.0f;
    }
    __syncthreads();

    if (tot <= PLACE_CAP) {
        for (int i = tid; i < tot; i += BLKP) {
            int rec = tmp[S + i];
            int nl = rec & 511;
            int s = rec >> 9;
            int q = (s >= t2) ? ((s >= t3) ? 3 : 2) : ((s >= t1) ? 1 : 0);
            int slot = ofs[nl] + cnt4[nl * 4 + q] + atomicAdd(&fill4[nl * 4 + q], 1);
            stage[slot] = s;
        }
        __syncthreads();
        for (int i = tid; i < tot; i += BLKP) psrc[S + i] = stage[i];
    } else {
        for (int i = tid; i < tot; i += BLKP) {
            int rec = tmp[S + i];
            int nl = rec & 511;
            int s = rec >> 9;
            int q = (s >= t2) ? ((s >= t3) ? 3 : 2) : ((s >= t1) ? 1 : 0);
            int slot = S + ofs[nl] + cnt4[nl * 4 + q] + atomicAdd(&fill4[nl * 4 + q], 1);
            psrc[slot] = s;
        }
    }
}

// z_k = x @ W1[k] for k=0..3; 2 lanes/node (8 outputs each).
__global__ __launch_bounds__(BLK)
void zgen_kernel(const float* __restrict__ x, const float* __restrict__ dis,
                 const float* __restrict__ W1,
                 uint4* __restrict__ z0t, uint4* __restrict__ uz1t,
                 uint4* __restrict__ uz2t, uint4* __restrict__ uz3t,
                 uint4* __restrict__ z2rt, int N) {
    __shared__ float sW[4 * 32 * 16];
    for (int i = threadIdx.x; i < 4 * 32 * 16; i += blockDim.x) sW[i] = W1[i];
    __syncthreads();
    int t = blockIdx.x * blockDim.x + threadIdx.x;
    int n = t >> 1;
    int h = t & 1;
    if (n >= N) return;
    float acc0[8], acc1[8], acc2[8], acc3[8];
#pragma unroll
    for (int j = 0; j < 8; j++) { acc0[j] = 0.f; acc1[j] = 0.f; acc2[j] = 0.f; acc3[j] = 0.f; }
    const float4* x4 = reinterpret_cast<const float4*>(x + (size_t)n * 32);
#pragma unroll
    for (int q = 0; q < 8; q++) {
        float4 a = x4[q];
        float xi[4] = {a.x, a.y, a.z, a.w};
#pragma unroll
        for (int u = 0; u < 4; u++) {
            const float* Wb = sW + (q * 4 + u) * 16 + h * 8;
            float xv = xi[u];
#pragma unroll
            for (int j = 0; j < 8; j++) {
                acc0[j] += xv * Wb[j];
                acc1[j] += xv * Wb[512 + j];
                acc2[j] += xv * Wb[1024 + j];
                acc3[j] += xv * Wb[1536 + j];
            }
        }
    }
    float dn = dis[n];
    float s1[8], s2[8], s3[8];
#pragma unroll
    for (int j = 0; j < 8; j++) { s1[j] = dn * acc1[j]; s2[j] = dn * acc2[j]; s3[j] = dn * acc3[j]; }
    size_t o = (size_t)n * 2 + h;
    z0t[o]  = pack8(acc0);
    uz1t[o] = pack8(s1);
    uz2t[o] = pack8(s2);
    z2rt[o] = pack8(acc2);
    uz3t[o] = pack8(s3);
}

// Clenshaw prop, 4 lanes/node: lane l -> chunk c=l&1, edge-half hf=l>>1.
// out = -2*d2[n]*Sum_e vb[src] + addt[n] (- subt[n]).
template <bool HAVE_SUB>
__global__ __launch_bounds__(BLK)
void prop_cl_kernel(const int* __restrict__ rowbeg, const int* __restrict__ rowend,
                    const int* __restrict__ psrc, const float* __restrict__ d2,
                    const uint4* __restrict__ vb, const uint4* __restrict__ addt,
                    const uint4* __restrict__ subt, uint4* __restrict__ outb, int N) {
    int t = blockIdx.x * blockDim.x + threadIdx.x;
    int n = t >> 2;
    int l = t & 3;
    int c = l & 1;
    int hf = l >> 1;
    if (n >= N) return;
    int beg = rowbeg[n];
    int end = rowend[n];
    int mid = beg + ((end - beg) >> 1);
    int b = hf ? mid : beg;
    int e = hf ? end : mid;
    float acc[8];
#pragma unroll
    for (int j = 0; j < 8; j++) acc[j] = 0.f;
    gather_sum(psrc, b, e, vb, c, acc);
    // merge halves (lanes l and l^2)
#pragma unroll
    for (int j = 0; j < 8; j++) acc[j] += __shfl_xor(acc[j], 2);
    if (hf) return;
    float f = -2.0f * d2[n];
    float ad[8], r[8];
    unpack8(addt[(size_t)n * 2 + c], ad);
    if (HAVE_SUB) {
        float sb[8];
        unpack8(subt[(size_t)n * 2 + c], sb);
#pragma unroll
        for (int j = 0; j < 8; j++) r[j] = f * acc[j] + ad[j] - sb[j];
    } else {
#pragma unroll
        for (int j = 0; j < 8; j++) r[j] = f * acc[j] + ad[j];
    }
    outb[(size_t)n * 2 + c] = pack8(r);
}

// final1, 4 lanes/node (chunk h=l&1, edge-half hf=l>>1):
// S = z0 - dis*Sum Ub1[src] - inv*Ub2 (deg-0: z0 - z2r); h = relu(b1+S);
// then w_k = h @ W2[k] (16-padded cols) on half-0 lanes.
__global__ __launch_bounds__(BLK)
void final1_kernel(const int* __restrict__ rowbeg, const int* __restrict__ rowend,
                   const int* __restrict__ psrc, const float* __restrict__ dis,
                   const float* __restrict__ d2, const float* __restrict__ inv,
                   const uint4* __restrict__ ub1t, const uint4* __restrict__ ub2t,
                   const uint4* __restrict__ z0t, const uint4* __restrict__ z2rt,
                   const float* __restrict__ W2, const float* __restrict__ b1,
                   uint4* __restrict__ w0t, uint4* __restrict__ uw1t,
                   uint4* __restrict__ uw2t, uint4* __restrict__ uw3t,
                   uint4* __restrict__ w2rt, int N) {
    __shared__ float sW[4 * 16 * 16];   // W2 padded to 16 cols (zeros beyond col 9)
    __shared__ float sb1[16];
    for (int i = threadIdx.x; i < 4 * 16 * 16; i += blockDim.x) {
        int k = i >> 8, rem = i & 255, j = rem >> 4, o = rem & 15;
        sW[i] = (o < 10) ? W2[k * 160 + j * 10 + o] : 0.0f;
    }
    if (threadIdx.x < 16) sb1[threadIdx.x] = b1[threadIdx.x];
    __syncthreads();
    int t = blockIdx.x * blockDim.x + threadIdx.x;
    int n = t >> 2;
    int l = t & 3;
    int h = l & 1;
    int hf = l >> 1;
    if (n >= N) return;
    int beg = rowbeg[n];
    int end = rowend[n];
    int mid = beg + ((end - beg) >> 1);
    int gb = hf ? mid : beg;
    int ge = hf ? end : mid;
    float acc[8];
#pragma unroll
    for (int j = 0; j < 8; j++) acc[j] = 0.f;
    gather_sum(psrc, gb, ge, ub1t, h, acc);
#pragma unroll
    for (int j = 0; j < 8; j++) acc[j] += __shfl_xor(acc[j], 2);
    if (hf) return;
    size_t o2 = (size_t)n * 2 + h;
    float z0[8], hrow[8];
    unpack8(z0t[o2], z0);
    if (d2[n] == 0.0f) {   // deg-0: S = z0 - z2
        float z2[8];
        unpack8(z2rt[o2], z2);
#pragma unroll
        for (int j = 0; j < 8; j++) hrow[j] = fmaxf(sb1[h * 8 + j] + z0[j] - z2[j], 0.0f);
    } else {
        float b2v[8];
        unpack8(ub2t[o2], b2v);
        float dn = dis[n], iv = inv[n];
#pragma unroll
        for (int j = 0; j < 8; j++)
            hrow[j] = fmaxf(sb1[h * 8 + j] + z0[j] - dn * acc[j] - iv * b2v[j], 0.0f);
    }
    // exchange halves -> full h16 (lanes 0,1 of the node group)
    float h16[16];
#pragma unroll
    for (int j = 0; j < 8; j++) {
        float other = __shfl_xor(hrow[j], 1);
        h16[h * 8 + j] = hrow[j];
        h16[(1 - h) * 8 + j] = other;
    }
    // w_k = h @ W2[k], this lane's 8 output cols (h*8 .. h*8+7)
    float w0[8], w1[8], w2[8], w3[8];
#pragma unroll
    for (int o = 0; o < 8; o++) { w0[o] = 0.f; w1[o] = 0.f; w2[o] = 0.f; w3[o] = 0.f; }
#pragma unroll
    for (int j = 0; j < 16; j++) {
        float hv = h16[j];
        const float* Wb = sW + j * 16 + h * 8;
#pragma unroll
        for (int o = 0; o < 8; o++) {
            w0[o] += hv * Wb[o];
            w1[o] += hv * Wb[256 + o];
            w2[o] += hv * Wb[512 + o];
            w3[o] += hv * Wb[768 + o];
        }
    }
    float dn = dis[n];
    float s1[8], s2[8], s3[8];
#pragma unroll
    for (int o = 0; o < 8; o++) { s1[o] = dn * w1[o]; s2[o] = dn * w2[o]; s3[o] = dn * w3[o]; }
    w0t[o2]  = pack8(w0);
    uw1t[o2] = pack8(s1);
    uw2t[o2] = pack8(s2);
    w2rt[o2] = pack8(w2);
    uw3t[o2] = pack8(s3);
}

// final2, 4 lanes/node: L = w0 - dis*Sum Uv1[src] - inv*Uv2 (deg-0: w0 - w2r);
// logits = b2 + L; log_softmax on half-0 lanes; lane0 writes 8, lane1 writes 2.
__global__ __launch_bounds__(BLK)
void final2_kernel(const int* __restrict__ rowbeg, const int* __restrict__ rowend,
                   const int* __restrict__ psrc, const float* __restrict__ dis,
                   const float* __restrict__ d2, const float* __restrict__ inv,
                   const uint4* __restrict__ uv1t, const uint4* __restrict__ uv2t,
                   const uint4* __restrict__ w0t, const uint4* __restrict__ w2rt,
                   const float* __restrict__ b2, float* __restrict__ out, int N) {
    __shared__ float sb2[16];
    if (threadIdx.x < 16) sb2[threadIdx.x] = (threadIdx.x < 10) ? b2[threadIdx.x] : 0.0f;
    __syncthreads();
    int t = blockIdx.x * blockDim.x + threadIdx.x;
    int n = t >> 2;
    int l = t & 3;
    int c = l & 1;
    int hf = l >> 1;
    if (n >= N) return;
    int beg = rowbeg[n];
    int end = rowend[n];
    int mid = beg + ((end - beg) >> 1);
    int gb = hf ? mid : beg;
    int ge = hf ? end : mid;
    float acc[8];
#pragma unroll
    for (int j = 0; j < 8; j++) acc[j] = 0.f;
    gather_sum(psrc, gb, ge, uv1t, c, acc);
#pragma unroll
    for (int j = 0; j < 8; j++) acc[j] += __shfl_xor(acc[j], 2);
    if (hf) return;
    size_t o2 = (size_t)n * 2 + c;
    float w0[8], L[8];
    unpack8(w0t[o2], w0);
    if (d2[n] == 0.0f) {
        float w2[8];
        unpack8(w2rt[o2], w2);
#pragma unroll
        for (int j = 0; j < 8; j++) L[j] = sb2[c * 8 + j] + w0[j] - w2[j];
    } else {
        float v2[8];
        unpack8(uv2t[o2], v2);
        float dn = dis[n], iv = inv[n];
#pragma unroll
        for (int j = 0; j < 8; j++)
            L[j] = sb2[c * 8 + j] + w0[j] - dn * acc[j] - iv * v2[j];
    }
    int nreal = (c == 0) ? 8 : 2;   // lane1 holds cols 8,9 (+6 pads)
    float m = -3.0e38f;
    for (int j = 0; j < nreal; j++) m = fmaxf(m, L[j]);
    m = fmaxf(m, __shfl_xor(m, 1));
    float s = 0.0f;
    for (int j = 0; j < nreal; j++) s += expf(L[j] - m);
    s += __shfl_xor(s, 1);
    float lse = m + logf(s);
    float* op = out + (size_t)n * 10 + c * 8;
    for (int j = 0; j < nreal; j++) op[j] = L[j] - lse;
}

extern "C" void kernel_launch(void* const* d_in, const int* in_sizes, int n_in,
                              void* d_out, int out_size, void* d_ws, size_t ws_size,
                              hipStream_t stream) {
    const float* x  = (const float*)d_in[0];
    const int*   ei = (const int*)d_in[1];
    const float* W1 = (const float*)d_in[2];
    const float* b1 = (const float*)d_in[3];
    const float* W2 = (const float*)d_in[4];
    const float* b2 = (const float*)d_in[5];
    float* out = (float*)d_out;

    const int N = in_sizes[0] / 32;   // 100000
    const int E = in_sizes[1] / 2;    // 1600000
    const int* src = ei;
    const int* dst = ei + E;

    const int nbuck = (N + 511) / 512;        // 196

    // workspace layout (16B-aligned); all feature tables are N x 32B (2 uint4)
    char* w = (char*)d_ws;
    int*   bfill  = (int*)w;              w += NBUCK_MAX * 4;
    int*   rowbeg = (int*)w;              w += (size_t)(N + 4) * 4;
    int*   rowend = (int*)w;              w += (size_t)(N + 4) * 4;
    float* dis    = (float*)w;            w += (size_t)N * 4;
    float* d2     = (float*)w;            w += (size_t)N * 4;
    float* inv    = (float*)w;            w += (size_t)N * 4;
    int*   tmp    = (int*)w;              w += (size_t)NBUCK_MAX * CAPB * 4;
    int*   psrc   = (int*)w;              w += (size_t)NBUCK_MAX * CAPB * 4;
    uint4* z0t    = (uint4*)w;            w += (size_t)32 * N;
    uint4* uz1t   = (uint4*)w;            w += (size_t)32 * N;
    uint4* uz2t   = (uint4*)w;            w += (size_t)32 * N;
    uint4* uz3t   = (uint4*)w;            w += (size_t)32 * N;
    uint4* z2rt   = (uint4*)w;            w += (size_t)32 * N;
    uint4* ub2t   = (uint4*)w;            w += (size_t)32 * N;
    uint4* ub1t   = (uint4*)w;            w += (size_t)32 * N;
    uint4* w0t    = (uint4*)w;            w += (size_t)32 * N;
    uint4* uw1t   = (uint4*)w;            w += (size_t)32 * N;
    uint4* uw2t   = (uint4*)w;            w += (size_t)32 * N;
    uint4* uw3t   = (uint4*)w;            w += (size_t)32 * N;
    uint4* w2rt   = (uint4*)w;            w += (size_t)32 * N;
    uint4* uv2t   = (uint4*)w;            w += (size_t)32 * N;
    uint4* uv1t   = (uint4*)w;            w += (size_t)32 * N;

    int gN2 = (N * 2 + BLK - 1) / BLK;    // 2 lanes/node (zgen)
    int gN4 = (N * 4 + BLK - 1) / BLK;    // 4 lanes/node (gather kernels)
    int gCH = (E + CHUNK - 1) / CHUNK;

    // ---- CSR build ----
    hipMemsetAsync(bfill, 0, NBUCK_MAX * sizeof(int), stream);
    binned_scatter_kernel<<<gCH, BLK, 0, stream>>>(src, dst, bfill, tmp, E, nbuck);
    bucket_place_kernel<<<nbuck, BLKP, 0, stream>>>(bfill, tmp, psrc, rowbeg, rowend,
                                                    dis, d2, inv, N);

    // ---- layer 1 (Clenshaw in 16-feature domain) ----
    zgen_kernel<<<gN2, BLK, 0, stream>>>(x, dis, W1, z0t, uz1t, uz2t, uz3t, z2rt, N);
    prop_cl_kernel<false><<<gN4, BLK, 0, stream>>>(rowbeg, rowend, psrc, d2,
                                                   uz3t, uz2t, nullptr, ub2t, N);
    prop_cl_kernel<true ><<<gN4, BLK, 0, stream>>>(rowbeg, rowend, psrc, d2,
                                                   ub2t, uz1t, uz3t, ub1t, N);
    final1_kernel<<<gN4, BLK, 0, stream>>>(rowbeg, rowend, psrc, dis, d2, inv,
                                           ub1t, ub2t, z0t, z2rt, W2, b1,
                                           w0t, uw1t, uw2t, uw3t, w2rt, N);

    // ---- layer 2 (Clenshaw in 10(->16)-feature domain) ----
    prop_cl_kernel<false><<<gN4, BLK, 0, stream>>>(rowbeg, rowend, psrc, d2,
                                                   uw3t, uw2t, nullptr, uv2t, N);
    prop_cl_kernel<true ><<<gN4, BLK, 0, stream>>>(rowbeg, rowend, psrc, d2,
                                                   uv2t, uw1t, uw3t, uv1t, N);
    final2_kernel<<<gN4, BLK, 0, stream>>>(rowbeg, rowend, psrc, dis, d2, inv,
                                           uv1t, uv2t, w0t, w2rt, b2, out, N);
}

// Round 21
// 246.183 us; speedup vs baseline: 1.0400x; 1.0400x over previous
//
#include <hip/hip_runtime.h>
#include <hip/hip_bf16.h>
#include <math.h>

// ChebyNet: 2-layer ChebConv (K=4), N=100000, E=1600000, F 32->16->10, log_softmax.
//
// R21: selective revert of R20. final1 with the 4-lane edge-split hit VGPR=124
// / 16% occupancy (dense w_k=h@W2[k] epilogue + gather-split machinery sized
// the register file for all phases) -> 47us. final1 reverts to R19's 2-lane
// form (lean regs, dense epilogue on all lanes). prop_cl/final2 KEEP the
// 4-lane edge-split (no dense epilogue -> lean registers; doubled waves cover
// gather latency).
// R18/R19 recap: Clenshaw (z_k = x@W1[k] first; all gathers in 16-feature
// domain, 3.2MB L2-resident tables), U-space folding, fixed-capacity bucket
// CSR build (CHUNK=4096), src-quartile edge ordering, deg-0 exact fallback.

#define BLK 256
#define BLKP 512
#define NBUCK_MAX 256   // buckets = ceil(N/512); requires N <= 131072
#define CHUNK 4096      // edges per binned_scatter block
#define CAPB 16384      // fixed capacity per bucket region in tmp/psrc
#define PLACE_CAP 10240 // LDS staging capacity in bucket_place (avg bucket 8192)

// ---------- bf16 helpers (storage-only quantization) ----------
__device__ inline unsigned short f32_to_bf16_rne(float f) {
    unsigned int u = __float_as_uint(f);
    unsigned int rounding = 0x7FFFu + ((u >> 16) & 1u);
    return (unsigned short)((u + rounding) >> 16);
}
__device__ inline unsigned int pack_bf16x2(float a, float b) {
    return (unsigned int)f32_to_bf16_rne(a) | ((unsigned int)f32_to_bf16_rne(b) << 16);
}
__device__ inline void unpack8(const uint4 u, float* f) {
    const unsigned int* p = &u.x;
#pragma unroll
    for (int j = 0; j < 4; j++) {
        unsigned int w = p[j];
        f[2 * j]     = __uint_as_float(w << 16);
        f[2 * j + 1] = __uint_as_float(w & 0xFFFF0000u);
    }
}
__device__ inline void add8(const uint4 u, float* acc) {
    const unsigned int* p = &u.x;
#pragma unroll
    for (int j = 0; j < 4; j++) {
        unsigned int w = p[j];
        acc[2 * j]     += __uint_as_float(w << 16);
        acc[2 * j + 1] += __uint_as_float(w & 0xFFFF0000u);
    }
}
__device__ inline uint4 pack8(const float* r) {
    uint4 o;
    o.x = pack_bf16x2(r[0], r[1]);
    o.y = pack_bf16x2(r[2], r[3]);
    o.z = pack_bf16x2(r[4], r[5]);
    o.w = pack_bf16x2(r[6], r[7]);
    return o;
}

// gather-sum over psrc[b,e) of vb chunk c
__device__ inline void gather_sum(const int* __restrict__ psrc, int b, int e,
                                  const uint4* __restrict__ vb, int c, float* acc) {
    int i = b;
    for (; i + 7 < e; i += 8) {
        int s0 = psrc[i],     s1 = psrc[i + 1], s2 = psrc[i + 2], s3 = psrc[i + 3];
        int s4 = psrc[i + 4], s5 = psrc[i + 5], s6 = psrc[i + 6], s7 = psrc[i + 7];
        uint4 a0 = vb[(size_t)s0 * 2 + c];
        uint4 a1 = vb[(size_t)s1 * 2 + c];
        uint4 a2 = vb[(size_t)s2 * 2 + c];
        uint4 a3 = vb[(size_t)s3 * 2 + c];
        uint4 a4 = vb[(size_t)s4 * 2 + c];
        uint4 a5 = vb[(size_t)s5 * 2 + c];
        uint4 a6 = vb[(size_t)s6 * 2 + c];
        uint4 a7 = vb[(size_t)s7 * 2 + c];
        add8(a0, acc); add8(a1, acc); add8(a2, acc); add8(a3, acc);
        add8(a4, acc); add8(a5, acc); add8(a6, acc); add8(a7, acc);
    }
    for (; i + 3 < e; i += 4) {
        int s0 = psrc[i], s1 = psrc[i + 1], s2 = psrc[i + 2], s3 = psrc[i + 3];
        uint4 a0 = vb[(size_t)s0 * 2 + c];
        uint4 a1 = vb[(size_t)s1 * 2 + c];
        uint4 a2 = vb[(size_t)s2 * 2 + c];
        uint4 a3 = vb[(size_t)s3 * 2 + c];
        add8(a0, acc); add8(a1, acc); add8(a2, acc); add8(a3, acc);
    }
    for (; i < e; i++) add8(vb[(size_t)psrc[i] * 2 + c], acc);
}

// ---------- CSR build (fixed-capacity buckets) ----------
__global__ __launch_bounds__(BLK)
void binned_scatter_kernel(const int* __restrict__ src, const int* __restrict__ dst,
                           int* __restrict__ bfill, int* __restrict__ tmp,
                           int E, int nbuck) {
    __shared__ int cnt[NBUCK_MAX];
    __shared__ int lofs[NBUCK_MAX + 1];
    __shared__ int pos[NBUCK_MAX];
    __shared__ int gbase[NBUCK_MAX];
    __shared__ int stage[CHUNK];
    __shared__ unsigned char bkt[CHUNK];

    int tid = threadIdx.x;
    int e0 = blockIdx.x * CHUNK;
    int nE = min(CHUNK, E - e0);

    for (int b = tid; b < nbuck; b += BLK) { cnt[b] = 0; pos[b] = 0; }
    __syncthreads();

    for (int i = tid; i < nE; i += BLK) {
        int d = dst[e0 + i];
        atomicAdd(&cnt[d >> 9], 1);
    }
    __syncthreads();

    {
        int v = (tid < nbuck) ? cnt[tid] : 0;
        lofs[tid] = v;
        __syncthreads();
        for (int off = 1; off < BLK; off <<= 1) {
            int t = (tid >= off) ? lofs[tid - off] : 0;
            __syncthreads();
            lofs[tid] += t;
            __syncthreads();
        }
        int incl = lofs[tid];
        __syncthreads();
        lofs[tid] = incl - v;
        if (tid == 0) lofs[nbuck] = nE;
        if (tid < nbuck && v > 0)
            gbase[tid] = tid * CAPB + atomicAdd(&bfill[tid], v);
    }
    __syncthreads();

    for (int i = tid; i < nE; i += BLK) {
        int s = src[e0 + i];
        int d = dst[e0 + i];
        int b = d >> 9;
        int slot = lofs[b] + atomicAdd(&pos[b], 1);
        stage[slot] = (s << 9) | (d & 511);
        bkt[slot] = (unsigned char)b;
    }
    __syncthreads();

    for (int i = tid; i < nE; i += BLK) {
        int b = bkt[i];
        tmp[gbase[b] + (i - lofs[b])] = stage[i];
    }
}

// Phase 2: per-bucket degree count/scan -> rowbeg/rowend/dis/d2/inv;
// rank+stage+flush psrc with each node's edges ordered by src quartile.
__global__ __launch_bounds__(BLKP)
void bucket_place_kernel(const int* __restrict__ bfill, const int* __restrict__ tmp,
                         int* __restrict__ psrc, int* __restrict__ rowbeg,
                         int* __restrict__ rowend, float* __restrict__ dis,
                         float* __restrict__ d2, float* __restrict__ inv, int N) {
    __shared__ int cnt4[512 * 4];
    __shared__ int ofs[512];
    __shared__ int fill4[512 * 4];
    __shared__ int stage[PLACE_CAP];

    int b = blockIdx.x;
    int tid = threadIdx.x;
    int n0 = b << 9;
    int nn = min(512, N - n0);
    int S = b * CAPB;
    int tot = bfill[b];

    int t1 = N >> 2, t2 = N >> 1, t3 = t2 + t1;

    for (int i = tid; i < 512 * 4; i += BLKP) { cnt4[i] = 0; fill4[i] = 0; }
    __syncthreads();

    for (int i = tid; i < tot; i += BLKP) {
        int rec = tmp[S + i];
        int nl = rec & 511;
        int s = rec >> 9;
        int q = (s >= t2) ? ((s >= t3) ? 3 : 2) : ((s >= t1) ? 1 : 0);
        atomicAdd(&cnt4[nl * 4 + q], 1);
    }
    __syncthreads();

    int c0 = cnt4[tid * 4 + 0], c1 = cnt4[tid * 4 + 1];
    int c2 = cnt4[tid * 4 + 2], c3 = cnt4[tid * 4 + 3];
    int v = c0 + c1 + c2 + c3;
    cnt4[tid * 4 + 0] = 0;
    cnt4[tid * 4 + 1] = c0;
    cnt4[tid * 4 + 2] = c0 + c1;
    cnt4[tid * 4 + 3] = c0 + c1 + c2;
    ofs[tid] = v;
    __syncthreads();
    for (int off = 1; off < 512; off <<= 1) {
        int t = (tid >= off) ? ofs[tid - off] : 0;
        __syncthreads();
        ofs[tid] += t;
        __syncthreads();
    }
    int excl = ofs[tid] - v;
    __syncthreads();
    ofs[tid] = excl;
    if (tid < nn) {
        int n = n0 + tid;
        rowbeg[n] = S + excl;
        rowend[n] = S + excl + v;
        float fv = (float)v;
        dis[n] = (v > 0) ? rsqrtf(fv) : 0.0f;
        d2[n]  = (v > 0) ? 1.0f / fv : 0.0f;
        inv[n] = (v > 0) ? sqrtf(fv) : 0.0f;
    }
    __syncthreads();

    if (tot <= PLACE_CAP) {
        for (int i = tid; i < tot; i += BLKP) {
            int rec = tmp[S + i];
            int nl = rec & 511;
            int s = rec >> 9;
            int q = (s >= t2) ? ((s >= t3) ? 3 : 2) : ((s >= t1) ? 1 : 0);
            int slot = ofs[nl] + cnt4[nl * 4 + q] + atomicAdd(&fill4[nl * 4 + q], 1);
            stage[slot] = s;
        }
        __syncthreads();
        for (int i = tid; i < tot; i += BLKP) psrc[S + i] = stage[i];
    } else {
        for (int i = tid; i < tot; i += BLKP) {
            int rec = tmp[S + i];
            int nl = rec & 511;
            int s = rec >> 9;
            int q = (s >= t2) ? ((s >= t3) ? 3 : 2) : ((s >= t1) ? 1 : 0);
            int slot = S + ofs[nl] + cnt4[nl * 4 + q] + atomicAdd(&fill4[nl * 4 + q], 1);
            psrc[slot] = s;
        }
    }
}

// z_k = x @ W1[k] for k=0..3; 2 lanes/node (8 outputs each).
__global__ __launch_bounds__(BLK)
void zgen_kernel(const float* __restrict__ x, const float* __restrict__ dis,
                 const float* __restrict__ W1,
                 uint4* __restrict__ z0t, uint4* __restrict__ uz1t,
                 uint4* __restrict__ uz2t, uint4* __restrict__ uz3t,
                 uint4* __restrict__ z2rt, int N) {
    __shared__ float sW[4 * 32 * 16];
    for (int i = threadIdx.x; i < 4 * 32 * 16; i += blockDim.x) sW[i] = W1[i];
    __syncthreads();
    int t = blockIdx.x * blockDim.x + threadIdx.x;
    int n = t >> 1;
    int h = t & 1;
    if (n >= N) return;
    float acc0[8], acc1[8], acc2[8], acc3[8];
#pragma unroll
    for (int j = 0; j < 8; j++) { acc0[j] = 0.f; acc1[j] = 0.f; acc2[j] = 0.f; acc3[j] = 0.f; }
    const float4* x4 = reinterpret_cast<const float4*>(x + (size_t)n * 32);
#pragma unroll
    for (int q = 0; q < 8; q++) {
        float4 a = x4[q];
        float xi[4] = {a.x, a.y, a.z, a.w};
#pragma unroll
        for (int u = 0; u < 4; u++) {
            const float* Wb = sW + (q * 4 + u) * 16 + h * 8;
            float xv = xi[u];
#pragma unroll
            for (int j = 0; j < 8; j++) {
                acc0[j] += xv * Wb[j];
                acc1[j] += xv * Wb[512 + j];
                acc2[j] += xv * Wb[1024 + j];
                acc3[j] += xv * Wb[1536 + j];
            }
        }
    }
    float dn = dis[n];
    float s1[8], s2[8], s3[8];
#pragma unroll
    for (int j = 0; j < 8; j++) { s1[j] = dn * acc1[j]; s2[j] = dn * acc2[j]; s3[j] = dn * acc3[j]; }
    size_t o = (size_t)n * 2 + h;
    z0t[o]  = pack8(acc0);
    uz1t[o] = pack8(s1);
    uz2t[o] = pack8(s2);
    z2rt[o] = pack8(acc2);
    uz3t[o] = pack8(s3);
}

// Clenshaw prop, 4 lanes/node: lane l -> chunk c=l&1, edge-half hf=l>>1.
// out = -2*d2[n]*Sum_e vb[src] + addt[n] (- subt[n]).
template <bool HAVE_SUB>
__global__ __launch_bounds__(BLK)
void prop_cl_kernel(const int* __restrict__ rowbeg, const int* __restrict__ rowend,
                    const int* __restrict__ psrc, const float* __restrict__ d2,
                    const uint4* __restrict__ vb, const uint4* __restrict__ addt,
                    const uint4* __restrict__ subt, uint4* __restrict__ outb, int N) {
    int t = blockIdx.x * blockDim.x + threadIdx.x;
    int n = t >> 2;
    int l = t & 3;
    int c = l & 1;
    int hf = l >> 1;
    if (n >= N) return;
    int beg = rowbeg[n];
    int end = rowend[n];
    int mid = beg + ((end - beg) >> 1);
    int b = hf ? mid : beg;
    int e = hf ? end : mid;
    float acc[8];
#pragma unroll
    for (int j = 0; j < 8; j++) acc[j] = 0.f;
    gather_sum(psrc, b, e, vb, c, acc);
#pragma unroll
    for (int j = 0; j < 8; j++) acc[j] += __shfl_xor(acc[j], 2);
    if (hf) return;
    float f = -2.0f * d2[n];
    float ad[8], r[8];
    unpack8(addt[(size_t)n * 2 + c], ad);
    if (HAVE_SUB) {
        float sb[8];
        unpack8(subt[(size_t)n * 2 + c], sb);
#pragma unroll
        for (int j = 0; j < 8; j++) r[j] = f * acc[j] + ad[j] - sb[j];
    } else {
#pragma unroll
        for (int j = 0; j < 8; j++) r[j] = f * acc[j] + ad[j];
    }
    outb[(size_t)n * 2 + c] = pack8(r);
}

// final1 (R19 2-lane form): S = z0 - dis*Sum Ub1[src] - inv*Ub2 (deg-0: z0-z2r);
// h = relu(b1+S); w_k = h @ W2[k] (16-padded cols).
__global__ __launch_bounds__(BLK)
void final1_kernel(const int* __restrict__ rowbeg, const int* __restrict__ rowend,
                   const int* __restrict__ psrc, const float* __restrict__ dis,
                   const float* __restrict__ d2, const float* __restrict__ inv,
                   const uint4* __restrict__ ub1t, const uint4* __restrict__ ub2t,
                   const uint4* __restrict__ z0t, const uint4* __restrict__ z2rt,
                   const float* __restrict__ W2, const float* __restrict__ b1,
                   uint4* __restrict__ w0t, uint4* __restrict__ uw1t,
                   uint4* __restrict__ uw2t, uint4* __restrict__ uw3t,
                   uint4* __restrict__ w2rt, int N) {
    __shared__ float sW[4 * 16 * 16];   // W2 padded to 16 cols (zeros beyond col 9)
    __shared__ float sb1[16];
    for (int i = threadIdx.x; i < 4 * 16 * 16; i += blockDim.x) {
        int k = i >> 8, rem = i & 255, j = rem >> 4, o = rem & 15;
        sW[i] = (o < 10) ? W2[k * 160 + j * 10 + o] : 0.0f;
    }
    if (threadIdx.x < 16) sb1[threadIdx.x] = b1[threadIdx.x];
    __syncthreads();
    int t = blockIdx.x * blockDim.x + threadIdx.x;
    int n = t >> 1;
    int h = t & 1;
    if (n >= N) return;
    int beg = rowbeg[n];
    int end = rowend[n];
    float acc[8];
#pragma unroll
    for (int j = 0; j < 8; j++) acc[j] = 0.f;
    gather_sum(psrc, beg, end, ub1t, h, acc);
    size_t o2 = (size_t)n * 2 + h;
    float z0[8], hrow[8];
    unpack8(z0t[o2], z0);
    if (d2[n] == 0.0f) {   // deg-0: S = z0 - z2
        float z2[8];
        unpack8(z2rt[o2], z2);
#pragma unroll
        for (int j = 0; j < 8; j++) hrow[j] = fmaxf(sb1[h * 8 + j] + z0[j] - z2[j], 0.0f);
    } else {
        float b2v[8];
        unpack8(ub2t[o2], b2v);
        float dn = dis[n], iv = inv[n];
#pragma unroll
        for (int j = 0; j < 8; j++)
            hrow[j] = fmaxf(sb1[h * 8 + j] + z0[j] - dn * acc[j] - iv * b2v[j], 0.0f);
    }
    // exchange halves -> full h16
    float h16[16];
#pragma unroll
    for (int j = 0; j < 8; j++) {
        float other = __shfl_xor(hrow[j], 1);
        h16[h * 8 + j] = hrow[j];
        h16[(1 - h) * 8 + j] = other;
    }
    // w_k = h @ W2[k], this lane's 8 output cols (h*8 .. h*8+7)
    float w0[8], w1[8], w2[8], w3[8];
#pragma unroll
    for (int o = 0; o < 8; o++) { w0[o] = 0.f; w1[o] = 0.f; w2[o] = 0.f; w3[o] = 0.f; }
#pragma unroll
    for (int j = 0; j < 16; j++) {
        float hv = h16[j];
        const float* Wb = sW + j * 16 + h * 8;
#pragma unroll
        for (int o = 0; o < 8; o++) {
            w0[o] += hv * Wb[o];
            w1[o] += hv * Wb[256 + o];
            w2[o] += hv * Wb[512 + o];
            w3[o] += hv * Wb[768 + o];
        }
    }
    float dn = dis[n];
    float s1[8], s2[8], s3[8];
#pragma unroll
    for (int o = 0; o < 8; o++) { s1[o] = dn * w1[o]; s2[o] = dn * w2[o]; s3[o] = dn * w3[o]; }
    w0t[o2]  = pack8(w0);
    uw1t[o2] = pack8(s1);
    uw2t[o2] = pack8(s2);
    w2rt[o2] = pack8(w2);
    uw3t[o2] = pack8(s3);
}

// final2, 4 lanes/node: L = w0 - dis*Sum Uv1[src] - inv*Uv2 (deg-0: w0 - w2r);
// logits = b2 + L; log_softmax on half-0 lanes; lane0 writes 8, lane1 writes 2.
__global__ __launch_bounds__(BLK)
void final2_kernel(const int* __restrict__ rowbeg, const int* __restrict__ rowend,
                   const int* __restrict__ psrc, const float* __restrict__ dis,
                   const float* __restrict__ d2, const float* __restrict__ inv,
                   const uint4* __restrict__ uv1t, const uint4* __restrict__ uv2t,
                   const uint4* __restrict__ w0t, const uint4* __restrict__ w2rt,
                   const float* __restrict__ b2, float* __restrict__ out, int N) {
    __shared__ float sb2[16];
    if (threadIdx.x < 16) sb2[threadIdx.x] = (threadIdx.x < 10) ? b2[threadIdx.x] : 0.0f;
    __syncthreads();
    int t = blockIdx.x * blockDim.x + threadIdx.x;
    int n = t >> 2;
    int l = t & 3;
    int c = l & 1;
    int hf = l >> 1;
    if (n >= N) return;
    int beg = rowbeg[n];
    int end = rowend[n];
    int mid = beg + ((end - beg) >> 1);
    int gb = hf ? mid : beg;
    int ge = hf ? end : mid;
    float acc[8];
#pragma unroll
    for (int j = 0; j < 8; j++) acc[j] = 0.f;
    gather_sum(psrc, gb, ge, uv1t, c, acc);
#pragma unroll
    for (int j = 0; j < 8; j++) acc[j] += __shfl_xor(acc[j], 2);
    if (hf) return;
    size_t o2 = (size_t)n * 2 + c;
    float w0[8], L[8];
    unpack8(w0t[o2], w0);
    if (d2[n] == 0.0f) {
        float w2[8];
        unpack8(w2rt[o2], w2);
#pragma unroll
        for (int j = 0; j < 8; j++) L[j] = sb2[c * 8 + j] + w0[j] - w2[j];
    } else {
        float v2[8];
        unpack8(uv2t[o2], v2);
        float dn = dis[n], iv = inv[n];
#pragma unroll
        for (int j = 0; j < 8; j++)
            L[j] = sb2[c * 8 + j] + w0[j] - dn * acc[j] - iv * v2[j];
    }
    int nreal = (c == 0) ? 8 : 2;   // lane1 holds cols 8,9 (+6 pads)
    float m = -3.0e38f;
    for (int j = 0; j < nreal; j++) m = fmaxf(m, L[j]);
    m = fmaxf(m, __shfl_xor(m, 1));
    float s = 0.0f;
    for (int j = 0; j < nreal; j++) s += expf(L[j] - m);
    s += __shfl_xor(s, 1);
    float lse = m + logf(s);
    float* op = out + (size_t)n * 10 + c * 8;
    for (int j = 0; j < nreal; j++) op[j] = L[j] - lse;
}

extern "C" void kernel_launch(void* const* d_in, const int* in_sizes, int n_in,
                              void* d_out, int out_size, void* d_ws, size_t ws_size,
                              hipStream_t stream) {
    const float* x  = (const float*)d_in[0];
    const int*   ei = (const int*)d_in[1];
    const float* W1 = (const float*)d_in[2];
    const float* b1 = (const float*)d_in[3];
    const float* W2 = (const float*)d_in[4];
    const float* b2 = (const float*)d_in[5];
    float* out = (float*)d_out;

    const int N = in_sizes[0] / 32;   // 100000
    const int E = in_sizes[1] / 2;    // 1600000
    const int* src = ei;
    const int* dst = ei + E;

    const int nbuck = (N + 511) / 512;        // 196

    // workspace layout (16B-aligned); all feature tables are N x 32B (2 uint4)
    char* w = (char*)d_ws;
    int*   bfill  = (int*)w;              w += NBUCK_MAX * 4;
    int*   rowbeg = (int*)w;              w += (size_t)(N + 4) * 4;
    int*   rowend = (int*)w;              w += (size_t)(N + 4) * 4;
    float* dis    = (float*)w;            w += (size_t)N * 4;
    float* d2     = (float*)w;            w += (size_t)N * 4;
    float* inv    = (float*)w;            w += (size_t)N * 4;
    int*   tmp    = (int*)w;              w += (size_t)NBUCK_MAX * CAPB * 4;
    int*   psrc   = (int*)w;              w += (size_t)NBUCK_MAX * CAPB * 4;
    uint4* z0t    = (uint4*)w;            w += (size_t)32 * N;
    uint4* uz1t   = (uint4*)w;            w += (size_t)32 * N;
    uint4* uz2t   = (uint4*)w;            w += (size_t)32 * N;
    uint4* uz3t   = (uint4*)w;            w += (size_t)32 * N;
    uint4* z2rt   = (uint4*)w;            w += (size_t)32 * N;
    uint4* ub2t   = (uint4*)w;            w += (size_t)32 * N;
    uint4* ub1t   = (uint4*)w;            w += (size_t)32 * N;
    uint4* w0t    = (uint4*)w;            w += (size_t)32 * N;
    uint4* uw1t   = (uint4*)w;            w += (size_t)32 * N;
    uint4* uw2t   = (uint4*)w;            w += (size_t)32 * N;
    uint4* uw3t   = (uint4*)w;            w += (size_t)32 * N;
    uint4* w2rt   = (uint4*)w;            w += (size_t)32 * N;
    uint4* uv2t   = (uint4*)w;            w += (size_t)32 * N;
    uint4* uv1t   = (uint4*)w;            w += (size_t)32 * N;

    int gN2 = (N * 2 + BLK - 1) / BLK;    // 2 lanes/node (zgen, final1)
    int gN4 = (N * 4 + BLK - 1) / BLK;    // 4 lanes/node (prop_cl, final2)
    int gCH = (E + CHUNK - 1) / CHUNK;

    // ---- CSR build ----
    hipMemsetAsync(bfill, 0, NBUCK_MAX * sizeof(int), stream);
    binned_scatter_kernel<<<gCH, BLK, 0, stream>>>(src, dst, bfill, tmp, E, nbuck);
    bucket_place_kernel<<<nbuck, BLKP, 0, stream>>>(bfill, tmp, psrc, rowbeg, rowend,
                                                    dis, d2, inv, N);

    // ---- layer 1 (Clenshaw in 16-feature domain) ----
    zgen_kernel<<<gN2, BLK, 0, stream>>>(x, dis, W1, z0t, uz1t, uz2t, uz3t, z2rt, N);
    prop_cl_kernel<false><<<gN4, BLK, 0, stream>>>(rowbeg, rowend, psrc, d2,
                                                   uz3t, uz2t, nullptr, ub2t, N);
    prop_cl_kernel<true ><<<gN4, BLK, 0, stream>>>(rowbeg, rowend, psrc, d2,
                                                   ub2t, uz1t, uz3t, ub1t, N);
    final1_kernel<<<gN2, BLK, 0, stream>>>(rowbeg, rowend, psrc, dis, d2, inv,
                                           ub1t, ub2t, z0t, z2rt, W2, b1,
                                           w0t, uw1t, uw2t, uw3t, w2rt, N);

    // ---- layer 2 (Clenshaw in 10(->16)-feature domain) ----
    prop_cl_kernel<false><<<gN4, BLK, 0, stream>>>(rowbeg, rowend, psrc, d2,
                                                   uw3t, uw2t, nullptr, uv2t, N);
    prop_cl_kernel<true ><<<gN4, BLK, 0, stream>>>(rowbeg, rowend, psrc, d2,
                                                   uv2t, uw1t, uw3t, uv1t, N);
    final2_kernel<<<gN4, BLK, 0, stream>>>(rowbeg, rowend, psrc, dis, d2, inv,
                                           uv1t, uv2t, w0t, w2rt, b2, out, N);
}